// Round 16
// baseline (105.064 us; speedup 1.0000x reference)
//
#include <hip/hip_runtime.h>
#include <hip/hip_fp16.h>

// GCN 2-layer + linear head on MI355X.
// out = relu(agg(relu(agg(X)@W1 + b1)@W2) + b2) @ Wl + bl
// agg(Y) = D^-1/2 (A+I) D^-1/2 Y  (commutes with the dense transform; layer 1
// aggregates X at 26 feats, layer 2 transforms first at 32 feats).
//
// Build: fixed 2048-slot region per 128-node bucket; per-chunk LDS hist -> one
// global atomicAdd per (chunk,bucket) range claim -> LDS-atomic scatter.
// Per-bucket degree/extents/node-sort + fp16 prescale; ALSO bitonic-sorts each
// 64-node tile by degree (desc) -> perm[] so gather waves get similar-degree
// nodes (kills the max-of-16 divergence, ~57% -> ~90% lane efficiency).
// Gathers: 4-lane groups, one node/group (degree-sorted via perm), half8/lane.
// Dense middle: MFMA (16x16x32 f16), fused behind gather1 (LDS handoff;
// gather writes row perm-node0, bijective per tile).
// Fragment maps (gfx950, HW-verified): A/B non-K index = lane&15, K-slice =
// (lane>>4)*8; C/D col=lane&15, row=(lane>>4)*4+reg.

#define TPB 256
#define NPB 128              // nodes per bucket (dstlow = 7 bits)
#define CAP 2048             // slots per bucket region (avg fill 1534, 13 sigma safe)
#define EPB 2048             // edges per scatter chunk (586 blocks -> better CU coverage)
#define NBUCK_MAX 1024

typedef _Float16 half8 __attribute__((ext_vector_type(8)));
typedef float floatx4 __attribute__((ext_vector_type(4)));

// ---- scatter: LDS hist -> bulk range claim -> scatter; + W transpose (blk 0) --

__global__ __launch_bounds__(TPB) void scatter_direct_kernel(
        const int* __restrict__ src, const int* __restrict__ dst,
        int* __restrict__ bcnt, int* __restrict__ sortedb,
        const float* __restrict__ W1, const float* __restrict__ W2,
        float* __restrict__ W1t, float* __restrict__ W2t,
        int e, int nbuck) {
    __shared__ int lh[NBUCK_MAX];
    int t = threadIdx.x;
    for (int b = t; b < nbuck; b += TPB) lh[b] = 0;
    __syncthreads();
    int j0 = blockIdx.x * EPB;
    int j1 = min(e, j0 + EPB);
    for (int j = j0 + t; j < j1; j += TPB)
        atomicAdd(&lh[dst[j] >> 7], 1);              // LDS hist
    __syncthreads();
    for (int b = t; b < nbuck; b += TPB) {
        int c = lh[b];
        int base = c ? atomicAdd(&bcnt[b], c) : 0;   // bulk global claim
        lh[b] = b * CAP + base;                      // running write ptr
    }
    __syncthreads();
    for (int j = j0 + t; j < j1; j += TPB) {
        int d = dst[j];
        int s = src[j];
        int pos = atomicAdd(&lh[d >> 7], 1);         // LDS atomic only
        sortedb[pos] = (s << 7) | (d & 127);
    }
    if (blockIdx.x == 0) {
        // W1t[64][32]: W1t[f*32+k] = W1[k*64+f] (k<26; pad 0). W2t[32][64].
        for (int q = t; q < 64 * 32; q += TPB) {
            int f = q >> 5, k = q & 31;
            W1t[q] = (k < 26) ? W1[k * 64 + f] : 0.0f;
        }
        for (int q = t; q < 32 * 64; q += TPB) {
            int f = q >> 6, k = q & 63;
            W2t[q] = W2[k * 32 + f];
        }
    }
}

// ---- per bucket: degrees -> dis/extents, node-sort, prescale, degree-perm ----

__global__ __launch_bounds__(TPB) void bucket_sort_fill_kernel(
        const int* __restrict__ sortedb, const int* __restrict__ bcnt,
        const float* __restrict__ x,
        int* __restrict__ slot, float* __restrict__ dis, int2* __restrict__ oe,
        __half* __restrict__ xs, int* __restrict__ perm, int n, int nbuck) {
    __shared__ int c[NPB];
    __shared__ int ptr[NPB];
    __shared__ float sdis[NPB];
    __shared__ int skey[NPB];
    __shared__ int sval[NPB];
    int b = blockIdx.x, t = threadIdx.x;
    if (t < NPB) c[t] = 0;
    __syncthreads();
    int start = b * CAP;
    int end = start + bcnt[b];
    for (int j = start + t; j < end; j += TPB)
        atomicAdd(&c[sortedb[j] & 127], 1);
    __syncthreads();
    int mycnt = (t < NPB) ? c[t] : 0;
    // inclusive Hillis-Steele scan over 128 entries
    for (int d = 1; d < NPB; d <<= 1) {
        int v = 0;
        if (t < NPB && t >= d) v = c[t - d];
        __syncthreads();
        if (t < NPB) c[t] += v;
        __syncthreads();
    }
    if (t < NPB) {
        int excl = c[t] - mycnt;
        ptr[t] = excl;
        float dv = rsqrtf((float)mycnt + 1.0f);
        sdis[t] = dv;
        int g = b * NPB + t;
        if (g < n) {
            dis[g] = dv;
            oe[g] = make_int2(start + excl, start + excl + mycnt);
        }
    }
    __syncthreads();
    for (int j = start + t; j < end; j += TPB) {
        int w = sortedb[j];
        int pos = atomicAdd(&ptr[w & 127], 1);  // LDS atomic only
        slot[start + pos] = w >> 7;
    }
    // fused prescale (fp16 padded 64B rows)
    int base = b * NPB;
    for (int i = t; i < NPB * 32; i += TPB) {
        int r = i >> 5, lane = i & 31;
        int g = base + r;
        if (g < n)
            xs[(size_t)g * 32 + lane] = __float2half(
                (lane < 26) ? sdis[r] * x[(size_t)g * 26 + lane] : 0.0f);
    }
    // degree-sort each 64-node half (one gather tile) desc -> perm
    if (t < NPB) { skey[t] = mycnt; sval[t] = t & 63; }
    __syncthreads();
    for (int k = 2; k <= 64; k <<= 1) {
        for (int jj = k >> 1; jj > 0; jj >>= 1) {
            if (t < NPB) {
                int i = t & 63;
                int ixj = i ^ jj;
                if (ixj > i) {
                    int h = t & 64;           // half offset (0 or 64)
                    int a = h + i, bx = h + ixj;
                    bool up = ((i & k) == 0);
                    int ka = skey[a], kb = skey[bx];
                    bool sw = up ? (ka < kb) : (ka > kb);   // descending blocks
                    if (sw) {
                        skey[a] = kb; skey[bx] = ka;
                        int va = sval[a]; sval[a] = sval[bx]; sval[bx] = va;
                    }
                }
            }
            __syncthreads();
        }
    }
    if (t < NPB) perm[b * NPB + t] = b * NPB + (t & 64) + sval[t];
}

// ---- fused gather1 + MFMA dense middle --------------------------------------
// Phase A: 64x 4-lane groups; group g handles node perm[node0+g] (degree-sorted),
//          half8/lane, unroll-4; writes LDS row (node - node0).
// Phase B: per-wave 16-node tile MFMA; h1 -> per-wave LDS; fp16 store.

__global__ __launch_bounds__(TPB) void gather1_dense_kernel(
        const __half* __restrict__ xs, const int2* __restrict__ oe,
        const int* __restrict__ slot, const float* __restrict__ dis,
        const int* __restrict__ perm,
        const float* __restrict__ W1t, const float* __restrict__ b1,
        const float* __restrict__ W2t, __half* __restrict__ xw2s, int n) {
    __shared__ _Float16 ssum[64][40];     // agg(X) tile: 64 nodes x 32 f (+8 pad)
    __shared__ _Float16 shh[4][16][72];   // h1: per-wave 16x64 (+8 pad)
    __shared__ _Float16 sho[4][16][40];   // out: per-wave 16x32 (+8 pad)
    __shared__ int sperm[64];
    int t = threadIdx.x;
    int node0 = blockIdx.x * 64;
    const _Float16* xsp = (const _Float16*)xs;

    if (t < 64) sperm[t] = perm[node0 + t];
    __syncthreads();

    // ---- phase A: gather (4 lanes per node, 8 feats per lane)
    {
        int g = t >> 2;              // 0..63 : node group
        int fl = (t & 3) * 8;        // feature chunk base
        int node = sperm[g];
        int nl = node - node0;       // LDS row (bijective within tile)
        float accf[8];
#pragma unroll
        for (int k = 0; k < 8; ++k) accf[k] = 0.0f;
        if (node < n) {
            half8 ownv = *(const half8*)(xsp + (size_t)node * 32 + fl);
#pragma unroll
            for (int k = 0; k < 8; ++k) accf[k] = (float)ownv[k];
            int2 se = oe[node];
            int j = se.x, end = se.y;
            for (; j + 3 < end; j += 4) {
                int s0 = slot[j], s1 = slot[j + 1], s2 = slot[j + 2], s3 = slot[j + 3];
                half8 v0 = *(const half8*)(xsp + (size_t)s0 * 32 + fl);
                half8 v1 = *(const half8*)(xsp + (size_t)s1 * 32 + fl);
                half8 v2 = *(const half8*)(xsp + (size_t)s2 * 32 + fl);
                half8 v3 = *(const half8*)(xsp + (size_t)s3 * 32 + fl);
#pragma unroll
                for (int k = 0; k < 8; ++k)
                    accf[k] += ((float)v0[k] + (float)v1[k]) + ((float)v2[k] + (float)v3[k]);
            }
            for (; j < end; ++j) {
                int s = slot[j];
                half8 v = *(const half8*)(xsp + (size_t)s * 32 + fl);
#pragma unroll
                for (int k = 0; k < 8; ++k) accf[k] += (float)v[k];
            }
        }
        half8 o;
#pragma unroll
        for (int k = 0; k < 8; ++k) o[k] = (_Float16)accf[k];
        *(half8*)&ssum[nl][fl] = o;
    }
    __syncthreads();

    // ---- phase B: MFMA dense middle
    int w = t >> 6, l = t & 63;
    int tnode0 = node0 + w * 16;
    int lm = l & 15;           // A/B non-K index
    int lk = l >> 4;           // K-slice id 0..3

    half8 a1 = *(const half8*)&ssum[w * 16 + lm][lk * 8];

    float dvv[4];
#pragma unroll
    for (int r = 0; r < 4; ++r) {
        int nd = tnode0 + lk * 4 + r;
        dvv[r] = dis[nd < n ? nd : (n - 1)];
    }

    // layer 1: 4 f-tiles of 16
#pragma unroll
    for (int T = 0; T < 4; ++T) {
        const float* bp = W1t + (size_t)(T * 16 + lm) * 32 + lk * 8;
        float4 bv0 = *(const float4*)bp;
        float4 bv1 = *(const float4*)(bp + 4);
        half8 bf;
        bf[0] = (_Float16)bv0.x; bf[1] = (_Float16)bv0.y;
        bf[2] = (_Float16)bv0.z; bf[3] = (_Float16)bv0.w;
        bf[4] = (_Float16)bv1.x; bf[5] = (_Float16)bv1.y;
        bf[6] = (_Float16)bv1.z; bf[7] = (_Float16)bv1.w;
        floatx4 c = {0.0f, 0.0f, 0.0f, 0.0f};
        c = __builtin_amdgcn_mfma_f32_16x16x32_f16(a1, bf, c, 0, 0, 0);
        float bias = b1[T * 16 + lm];
#pragma unroll
        for (int r = 0; r < 4; ++r) {
            float h = fmaxf(dvv[r] * c[r] + bias, 0.0f);
            shh[w][lk * 4 + r][T * 16 + lm] = (_Float16)h;
        }
    }

    // layer 2: A2 from per-wave LDS tile (node=lm), 2 K-steps x 2 f-tiles
    half8 a2k0 = *(const half8*)&shh[w][lm][lk * 8];
    half8 a2k1 = *(const half8*)&shh[w][lm][32 + lk * 8];
#pragma unroll
    for (int T = 0; T < 2; ++T) {
        const float* bp0 = W2t + (size_t)(T * 16 + lm) * 64 + lk * 8;
        const float* bp1 = bp0 + 32;
        float4 c0 = *(const float4*)bp0;
        float4 c1 = *(const float4*)(bp0 + 4);
        float4 c2 = *(const float4*)bp1;
        float4 c3 = *(const float4*)(bp1 + 4);
        half8 bf0, bf1;
        bf0[0] = (_Float16)c0.x; bf0[1] = (_Float16)c0.y;
        bf0[2] = (_Float16)c0.z; bf0[3] = (_Float16)c0.w;
        bf0[4] = (_Float16)c1.x; bf0[5] = (_Float16)c1.y;
        bf0[6] = (_Float16)c1.z; bf0[7] = (_Float16)c1.w;
        bf1[0] = (_Float16)c2.x; bf1[1] = (_Float16)c2.y;
        bf1[2] = (_Float16)c2.z; bf1[3] = (_Float16)c2.w;
        bf1[4] = (_Float16)c3.x; bf1[5] = (_Float16)c3.y;
        bf1[6] = (_Float16)c3.z; bf1[7] = (_Float16)c3.w;
        floatx4 acc = {0.0f, 0.0f, 0.0f, 0.0f};
        acc = __builtin_amdgcn_mfma_f32_16x16x32_f16(a2k0, bf0, acc, 0, 0, 0);
        acc = __builtin_amdgcn_mfma_f32_16x16x32_f16(a2k1, bf1, acc, 0, 0, 0);
#pragma unroll
        for (int r = 0; r < 4; ++r)
            sho[w][lk * 4 + r][T * 16 + lm] = (_Float16)(dvv[r] * acc[r]);
    }

    // coalesced store: lane -> node_local l>>2, f2-chunk (l&3)*8
    int nl = l >> 2, fc = (l & 3) * 8;
    int gnode = tnode0 + nl;
    if (gnode < n) {
        half8 v = *(const half8*)&sho[w][nl][fc];
        *(half8*)((_Float16*)xw2s + (size_t)gnode * 32 + fc) = v;
    }
}

// ---- layer 2 gather + bias + relu + head (degree-sorted 4-lane groups) -------

__global__ __launch_bounds__(TPB) void gather2_head_kernel(
        const __half* __restrict__ xw2s, const float* __restrict__ dis,
        const int2* __restrict__ oe, const int* __restrict__ slot,
        const int* __restrict__ perm,
        const float* __restrict__ b2, const float* __restrict__ Wl,
        const float* __restrict__ bl, float* __restrict__ out, int n) {
    __shared__ int sperm[64];
    int t = threadIdx.x;
    int node0 = blockIdx.x * 64;
    if (t < 64) sperm[t] = perm[node0 + t];
    __syncthreads();
    int g = t >> 2;              // 0..63 : node group
    int fl = (t & 3) * 8;        // feature chunk base
    int node = sperm[g];
    if (node >= n) return;
    const _Float16* xp = (const _Float16*)xw2s;

    float accf[8];
    half8 ownv = *(const half8*)(xp + (size_t)node * 32 + fl);
#pragma unroll
    for (int k = 0; k < 8; ++k) accf[k] = (float)ownv[k];
    int2 se = oe[node];
    int j = se.x, end = se.y;
    for (; j + 3 < end; j += 4) {
        int s0 = slot[j], s1 = slot[j + 1], s2 = slot[j + 2], s3 = slot[j + 3];
        half8 v0 = *(const half8*)(xp + (size_t)s0 * 32 + fl);
        half8 v1 = *(const half8*)(xp + (size_t)s1 * 32 + fl);
        half8 v2 = *(const half8*)(xp + (size_t)s2 * 32 + fl);
        half8 v3 = *(const half8*)(xp + (size_t)s3 * 32 + fl);
#pragma unroll
        for (int k = 0; k < 8; ++k)
            accf[k] += ((float)v0[k] + (float)v1[k]) + ((float)v2[k] + (float)v3[k]);
    }
    for (; j < end; ++j) {
        int s = slot[j];
        half8 v = *(const half8*)(xp + (size_t)s * 32 + fl);
#pragma unroll
        for (int k = 0; k < 8; ++k) accf[k] += (float)v[k];
    }

    float dv = dis[node];
    float4 bq0 = *(const float4*)(b2 + fl);
    float4 bq1 = *(const float4*)(b2 + fl + 4);
    float4 wq0 = *(const float4*)(Wl + fl);
    float4 wq1 = *(const float4*)(Wl + fl + 4);
    float bb[8] = {bq0.x, bq0.y, bq0.z, bq0.w, bq1.x, bq1.y, bq1.z, bq1.w};
    float wl[8] = {wq0.x, wq0.y, wq0.z, wq0.w, wq1.x, wq1.y, wq1.z, wq1.w};
    float c = 0.0f;
#pragma unroll
    for (int k = 0; k < 8; ++k) {
        float v = fmaxf(dv * accf[k] + bb[k], 0.0f);
        c += v * wl[k];
    }
    c += __shfl_xor(c, 1);
    c += __shfl_xor(c, 2);
    if ((t & 3) == 0) out[node] = c + bl[0];
}

// ---- host ------------------------------------------------------------------

extern "C" void kernel_launch(void* const* d_in, const int* in_sizes, int n_in,
                              void* d_out, int out_size, void* d_ws, size_t ws_size,
                              hipStream_t stream) {
    const float* x  = (const float*)d_in[0];
    const int*   ei = (const int*)d_in[1];
    const float* W1 = (const float*)d_in[2];
    const float* b1 = (const float*)d_in[3];
    const float* W2 = (const float*)d_in[4];
    const float* b2 = (const float*)d_in[5];
    const float* Wl = (const float*)d_in[6];
    const float* bl = (const float*)d_in[7];
    float* out = (float*)d_out;

    const int n = in_sizes[0] / 26;
    const int e = in_sizes[1] / 2;
    const int* src = ei;
    const int* dst = ei + e;

    const int nbuck = (n + NPB - 1) / NPB;   // 782 (<= NBUCK_MAX)
    const int eb    = (e + EPB - 1) / EPB;   // 586 scatter chunks

    auto align_up = [](size_t v) { return (v + 255) & ~(size_t)255; };
    char* p = (char*)d_ws;
    int*    bcnt    = (int*)p;     p += align_up((size_t)nbuck * 4);
    int*    sortedb = (int*)p;     p += align_up(((size_t)nbuck * CAP + 4096) * 4);
    int*    slot    = (int*)p;     p += align_up(((size_t)nbuck * CAP + 4096) * 4);
    float*  dis     = (float*)p;   p += align_up((size_t)n * 4);
    int2*   oe      = (int2*)p;    p += align_up((size_t)n * 8);
    int*    perm    = (int*)p;     p += align_up((size_t)nbuck * NPB * 4);
    float*  W1t     = (float*)p;   p += align_up(64 * 32 * 4);
    float*  W2t     = (float*)p;   p += align_up(32 * 64 * 4);
    __half* xs      = (__half*)p;  p += align_up((size_t)n * 32 * 2);
    __half* xw2s    = (__half*)p;  p += align_up((size_t)n * 32 * 2);

    // 1) build: zero bucket counters, scatter with bulk range claiming
    hipMemsetAsync(bcnt, 0, (size_t)nbuck * 4, stream);
    scatter_direct_kernel<<<eb, TPB, 0, stream>>>(src, dst, bcnt, sortedb,
                                                  W1, W2, W1t, W2t, e, nbuck);
    bucket_sort_fill_kernel<<<nbuck, TPB, 0, stream>>>(sortedb, bcnt, x, slot,
                                                       dis, oe, xs, perm, n, nbuck);

    // 2) fused layer-1 gather + MFMA dense middle (degree-sorted groups)
    gather1_dense_kernel<<<(n + 63) / 64, TPB, 0, stream>>>(xs, oe, slot, dis, perm,
                                                            W1t, b1, W2t, xw2s, n);

    // 3) layer 2 gather + bias + relu + head (fused, degree-sorted groups)
    gather2_head_kernel<<<(n + 63) / 64, TPB, 0, stream>>>(xw2s, dis, oe, slot, perm,
                                                           b2, Wl, bl, out, n);
}

// Round 17
// 96.920 us; speedup vs baseline: 1.0840x; 1.0840x over previous
//
#include <hip/hip_runtime.h>
#include <hip/hip_fp16.h>

// GCN 2-layer + linear head on MI355X.
// out = relu(agg(relu(agg(X)@W1 + b1)@W2) + b2) @ Wl + bl
// agg(Y) = D^-1/2 (A+I) D^-1/2 Y  (commutes with the dense transform; layer 1
// aggregates X at 26 feats, layer 2 transforms first at 32 feats).
//
// Build: fixed 2048-slot region per 128-node bucket; per-chunk LDS hist -> one
// global atomicAdd per (chunk,bucket) range claim -> LDS-atomic scatter. Then
// per-bucket degree/extents/node-sort/prescale (xs fp16, padded 64B rows).
// Gathers: 4-lane groups, one node/group, half8 (16B) per lane -> 8x fewer
// VMEM instructions per edge, 16 edge streams per wave, unroll-4 MLP.
// Dense middle: MFMA (16x16x32 f16), fused behind gather1 (LDS handoff).
// Fragment maps (gfx950, HW-verified): A/B non-K index = lane&15, K-slice =
// (lane>>4)*8; C/D col=lane&15, row=(lane>>4)*4+reg.
//
// R17 = exact revert to the verified R14 optimum (97.3 us). R15 (int4 slots:
// slot loads were already lane-broadcast) and R16 (degree-perm: destroyed
// L2 locality; halved EPB doubled scatter fixed costs) both regressed.

#define TPB 256
#define NPB 128              // nodes per bucket (dstlow = 7 bits)
#define CAP 2048             // slots per bucket region (avg fill 1534, 13 sigma safe)
#define EPB 4096             // edges per scatter chunk
#define NBUCK_MAX 1024

typedef _Float16 half8 __attribute__((ext_vector_type(8)));
typedef float floatx4 __attribute__((ext_vector_type(4)));

// ---- scatter: LDS hist -> bulk range claim -> scatter; + W transpose (blk 0) --

__global__ __launch_bounds__(TPB) void scatter_direct_kernel(
        const int* __restrict__ src, const int* __restrict__ dst,
        int* __restrict__ bcnt, int* __restrict__ sortedb,
        const float* __restrict__ W1, const float* __restrict__ W2,
        float* __restrict__ W1t, float* __restrict__ W2t,
        int e, int nbuck) {
    __shared__ int lh[NBUCK_MAX];
    int t = threadIdx.x;
    for (int b = t; b < nbuck; b += TPB) lh[b] = 0;
    __syncthreads();
    int j0 = blockIdx.x * EPB;
    int j1 = min(e, j0 + EPB);
    for (int j = j0 + t; j < j1; j += TPB)
        atomicAdd(&lh[dst[j] >> 7], 1);              // LDS hist
    __syncthreads();
    for (int b = t; b < nbuck; b += TPB) {
        int c = lh[b];
        int base = c ? atomicAdd(&bcnt[b], c) : 0;   // bulk global claim
        lh[b] = b * CAP + base;                      // running write ptr
    }
    __syncthreads();
    for (int j = j0 + t; j < j1; j += TPB) {
        int d = dst[j];
        int s = src[j];
        int pos = atomicAdd(&lh[d >> 7], 1);         // LDS atomic only
        sortedb[pos] = (s << 7) | (d & 127);
    }
    if (blockIdx.x == 0) {
        // W1t[64][32]: W1t[f*32+k] = W1[k*64+f] (k<26; pad 0). W2t[32][64].
        for (int q = t; q < 64 * 32; q += TPB) {
            int f = q >> 5, k = q & 31;
            W1t[q] = (k < 26) ? W1[k * 64 + f] : 0.0f;
        }
        for (int q = t; q < 32 * 64; q += TPB) {
            int f = q >> 6, k = q & 63;
            W2t[q] = W2[k * 32 + f];
        }
    }
}

// ---- per bucket: degree count -> dis/extents, node-sorted slots, prescale ----

__global__ __launch_bounds__(TPB) void bucket_sort_fill_kernel(
        const int* __restrict__ sortedb, const int* __restrict__ bcnt,
        const float* __restrict__ x,
        int* __restrict__ slot, float* __restrict__ dis, int2* __restrict__ oe,
        __half* __restrict__ xs, int n, int nbuck) {
    __shared__ int c[NPB];
    __shared__ int ptr[NPB];
    __shared__ float sdis[NPB];
    int b = blockIdx.x, t = threadIdx.x;
    if (t < NPB) c[t] = 0;
    __syncthreads();
    int start = b * CAP;
    int end = start + bcnt[b];
    for (int j = start + t; j < end; j += TPB)
        atomicAdd(&c[sortedb[j] & 127], 1);
    __syncthreads();
    int mycnt = (t < NPB) ? c[t] : 0;
    // inclusive Hillis-Steele scan over 128 entries
    for (int d = 1; d < NPB; d <<= 1) {
        int v = 0;
        if (t < NPB && t >= d) v = c[t - d];
        __syncthreads();
        if (t < NPB) c[t] += v;
        __syncthreads();
    }
    if (t < NPB) {
        int excl = c[t] - mycnt;
        ptr[t] = excl;
        float dv = rsqrtf((float)mycnt + 1.0f);
        sdis[t] = dv;
        int g = b * NPB + t;
        if (g < n) {
            dis[g] = dv;
            oe[g] = make_int2(start + excl, start + excl + mycnt);
        }
    }
    __syncthreads();
    for (int j = start + t; j < end; j += TPB) {
        int w = sortedb[j];
        int pos = atomicAdd(&ptr[w & 127], 1);  // LDS atomic only
        slot[start + pos] = w >> 7;
    }
    // fused prescale (fp16 padded 64B rows)
    int base = b * NPB;
    for (int i = t; i < NPB * 32; i += TPB) {
        int r = i >> 5, lane = i & 31;
        int g = base + r;
        if (g < n)
            xs[(size_t)g * 32 + lane] = __float2half(
                (lane < 26) ? sdis[r] * x[(size_t)g * 26 + lane] : 0.0f);
    }
}

// ---- fused gather1 + MFMA dense middle --------------------------------------
// Phase A: 64x 4-lane groups, one node each; half8/lane, unroll-4 edge streams.
// Phase B: per-wave 16-node tile MFMA; h1 -> per-wave LDS; fp16 store.

__global__ __launch_bounds__(TPB) void gather1_dense_kernel(
        const __half* __restrict__ xs, const int2* __restrict__ oe,
        const int* __restrict__ slot, const float* __restrict__ dis,
        const float* __restrict__ W1t, const float* __restrict__ b1,
        const float* __restrict__ W2t, __half* __restrict__ xw2s, int n) {
    __shared__ _Float16 ssum[64][40];     // agg(X) tile: 64 nodes x 32 f (+8 pad)
    __shared__ _Float16 shh[4][16][72];   // h1: per-wave 16x64 (+8 pad)
    __shared__ _Float16 sho[4][16][40];   // out: per-wave 16x32 (+8 pad)
    int t = threadIdx.x;
    int node0 = blockIdx.x * 64;
    const _Float16* xsp = (const _Float16*)xs;

    // ---- phase A: gather (4 lanes per node, 8 feats per lane)
    {
        int g = t >> 2;              // 0..63 : node group
        int fl = (t & 3) * 8;        // feature chunk base
        int node = node0 + g;
        float accf[8];
#pragma unroll
        for (int k = 0; k < 8; ++k) accf[k] = 0.0f;
        if (node < n) {
            half8 ownv = *(const half8*)(xsp + (size_t)node * 32 + fl);
#pragma unroll
            for (int k = 0; k < 8; ++k) accf[k] = (float)ownv[k];
            int2 se = oe[node];
            int j = se.x, end = se.y;
            for (; j + 3 < end; j += 4) {
                int s0 = slot[j], s1 = slot[j + 1], s2 = slot[j + 2], s3 = slot[j + 3];
                half8 v0 = *(const half8*)(xsp + (size_t)s0 * 32 + fl);
                half8 v1 = *(const half8*)(xsp + (size_t)s1 * 32 + fl);
                half8 v2 = *(const half8*)(xsp + (size_t)s2 * 32 + fl);
                half8 v3 = *(const half8*)(xsp + (size_t)s3 * 32 + fl);
#pragma unroll
                for (int k = 0; k < 8; ++k)
                    accf[k] += ((float)v0[k] + (float)v1[k]) + ((float)v2[k] + (float)v3[k]);
            }
            for (; j < end; ++j) {
                int s = slot[j];
                half8 v = *(const half8*)(xsp + (size_t)s * 32 + fl);
#pragma unroll
                for (int k = 0; k < 8; ++k) accf[k] += (float)v[k];
            }
        }
        half8 o;
#pragma unroll
        for (int k = 0; k < 8; ++k) o[k] = (_Float16)accf[k];
        *(half8*)&ssum[g][fl] = o;
    }
    __syncthreads();

    // ---- phase B: MFMA dense middle
    int w = t >> 6, l = t & 63;
    int tnode0 = node0 + w * 16;
    int lm = l & 15;           // A/B non-K index
    int lk = l >> 4;           // K-slice id 0..3

    half8 a1 = *(const half8*)&ssum[w * 16 + lm][lk * 8];

    float dvv[4];
#pragma unroll
    for (int r = 0; r < 4; ++r) {
        int nd = tnode0 + lk * 4 + r;
        dvv[r] = dis[nd < n ? nd : (n - 1)];
    }

    // layer 1: 4 f-tiles of 16
#pragma unroll
    for (int T = 0; T < 4; ++T) {
        const float* bp = W1t + (size_t)(T * 16 + lm) * 32 + lk * 8;
        float4 bv0 = *(const float4*)bp;
        float4 bv1 = *(const float4*)(bp + 4);
        half8 bf;
        bf[0] = (_Float16)bv0.x; bf[1] = (_Float16)bv0.y;
        bf[2] = (_Float16)bv0.z; bf[3] = (_Float16)bv0.w;
        bf[4] = (_Float16)bv1.x; bf[5] = (_Float16)bv1.y;
        bf[6] = (_Float16)bv1.z; bf[7] = (_Float16)bv1.w;
        floatx4 c = {0.0f, 0.0f, 0.0f, 0.0f};
        c = __builtin_amdgcn_mfma_f32_16x16x32_f16(a1, bf, c, 0, 0, 0);
        float bias = b1[T * 16 + lm];
#pragma unroll
        for (int r = 0; r < 4; ++r) {
            float h = fmaxf(dvv[r] * c[r] + bias, 0.0f);
            shh[w][lk * 4 + r][T * 16 + lm] = (_Float16)h;
        }
    }

    // layer 2: A2 from per-wave LDS tile (node=lm), 2 K-steps x 2 f-tiles
    half8 a2k0 = *(const half8*)&shh[w][lm][lk * 8];
    half8 a2k1 = *(const half8*)&shh[w][lm][32 + lk * 8];
#pragma unroll
    for (int T = 0; T < 2; ++T) {
        const float* bp0 = W2t + (size_t)(T * 16 + lm) * 64 + lk * 8;
        const float* bp1 = bp0 + 32;
        float4 c0 = *(const float4*)bp0;
        float4 c1 = *(const float4*)(bp0 + 4);
        float4 c2 = *(const float4*)bp1;
        float4 c3 = *(const float4*)(bp1 + 4);
        half8 bf0, bf1;
        bf0[0] = (_Float16)c0.x; bf0[1] = (_Float16)c0.y;
        bf0[2] = (_Float16)c0.z; bf0[3] = (_Float16)c0.w;
        bf0[4] = (_Float16)c1.x; bf0[5] = (_Float16)c1.y;
        bf0[6] = (_Float16)c1.z; bf0[7] = (_Float16)c1.w;
        bf1[0] = (_Float16)c2.x; bf1[1] = (_Float16)c2.y;
        bf1[2] = (_Float16)c2.z; bf1[3] = (_Float16)c2.w;
        bf1[4] = (_Float16)c3.x; bf1[5] = (_Float16)c3.y;
        bf1[6] = (_Float16)c3.z; bf1[7] = (_Float16)c3.w;
        floatx4 acc = {0.0f, 0.0f, 0.0f, 0.0f};
        acc = __builtin_amdgcn_mfma_f32_16x16x32_f16(a2k0, bf0, acc, 0, 0, 0);
        acc = __builtin_amdgcn_mfma_f32_16x16x32_f16(a2k1, bf1, acc, 0, 0, 0);
#pragma unroll
        for (int r = 0; r < 4; ++r)
            sho[w][lk * 4 + r][T * 16 + lm] = (_Float16)(dvv[r] * acc[r]);
    }

    // coalesced store: lane -> node_local l>>2, f2-chunk (l&3)*8
    int nl = l >> 2, fc = (l & 3) * 8;
    int gnode = tnode0 + nl;
    if (gnode < n) {
        half8 v = *(const half8*)&sho[w][nl][fc];
        *(half8*)((_Float16*)xw2s + (size_t)gnode * 32 + fc) = v;
    }
}

// ---- layer 2 gather + bias + relu + head (4-lane groups, half8/lane) ---------

__global__ __launch_bounds__(TPB) void gather2_head_kernel(
        const __half* __restrict__ xw2s, const float* __restrict__ dis,
        const int2* __restrict__ oe, const int* __restrict__ slot,
        const float* __restrict__ b2, const float* __restrict__ Wl,
        const float* __restrict__ bl, float* __restrict__ out, int n) {
    int t = threadIdx.x;
    int g = t >> 2;              // 0..63 : node group
    int fl = (t & 3) * 8;        // feature chunk base
    int node = blockIdx.x * 64 + g;
    if (node >= n) return;
    const _Float16* xp = (const _Float16*)xw2s;

    float accf[8];
    half8 ownv = *(const half8*)(xp + (size_t)node * 32 + fl);
#pragma unroll
    for (int k = 0; k < 8; ++k) accf[k] = (float)ownv[k];
    int2 se = oe[node];
    int j = se.x, end = se.y;
    for (; j + 3 < end; j += 4) {
        int s0 = slot[j], s1 = slot[j + 1], s2 = slot[j + 2], s3 = slot[j + 3];
        half8 v0 = *(const half8*)(xp + (size_t)s0 * 32 + fl);
        half8 v1 = *(const half8*)(xp + (size_t)s1 * 32 + fl);
        half8 v2 = *(const half8*)(xp + (size_t)s2 * 32 + fl);
        half8 v3 = *(const half8*)(xp + (size_t)s3 * 32 + fl);
#pragma unroll
        for (int k = 0; k < 8; ++k)
            accf[k] += ((float)v0[k] + (float)v1[k]) + ((float)v2[k] + (float)v3[k]);
    }
    for (; j < end; ++j) {
        int s = slot[j];
        half8 v = *(const half8*)(xp + (size_t)s * 32 + fl);
#pragma unroll
        for (int k = 0; k < 8; ++k) accf[k] += (float)v[k];
    }

    float dv = dis[node];
    float4 bq0 = *(const float4*)(b2 + fl);
    float4 bq1 = *(const float4*)(b2 + fl + 4);
    float4 wq0 = *(const float4*)(Wl + fl);
    float4 wq1 = *(const float4*)(Wl + fl + 4);
    float bb[8] = {bq0.x, bq0.y, bq0.z, bq0.w, bq1.x, bq1.y, bq1.z, bq1.w};
    float wl[8] = {wq0.x, wq0.y, wq0.z, wq0.w, wq1.x, wq1.y, wq1.z, wq1.w};
    float c = 0.0f;
#pragma unroll
    for (int k = 0; k < 8; ++k) {
        float v = fmaxf(dv * accf[k] + bb[k], 0.0f);
        c += v * wl[k];
    }
    c += __shfl_xor(c, 1);
    c += __shfl_xor(c, 2);
    if ((t & 3) == 0) out[node] = c + bl[0];
}

// ---- host ------------------------------------------------------------------

extern "C" void kernel_launch(void* const* d_in, const int* in_sizes, int n_in,
                              void* d_out, int out_size, void* d_ws, size_t ws_size,
                              hipStream_t stream) {
    const float* x  = (const float*)d_in[0];
    const int*   ei = (const int*)d_in[1];
    const float* W1 = (const float*)d_in[2];
    const float* b1 = (const float*)d_in[3];
    const float* W2 = (const float*)d_in[4];
    const float* b2 = (const float*)d_in[5];
    const float* Wl = (const float*)d_in[6];
    const float* bl = (const float*)d_in[7];
    float* out = (float*)d_out;

    const int n = in_sizes[0] / 26;
    const int e = in_sizes[1] / 2;
    const int* src = ei;
    const int* dst = ei + e;

    const int nbuck = (n + NPB - 1) / NPB;   // 782 (<= NBUCK_MAX)
    const int eb    = (e + EPB - 1) / EPB;   // 293 scatter chunks

    auto align_up = [](size_t v) { return (v + 255) & ~(size_t)255; };
    char* p = (char*)d_ws;
    int*    bcnt    = (int*)p;     p += align_up((size_t)nbuck * 4);
    int*    sortedb = (int*)p;     p += align_up(((size_t)nbuck * CAP + 4096) * 4);
    int*    slot    = (int*)p;     p += align_up(((size_t)nbuck * CAP + 4096) * 4);
    float*  dis     = (float*)p;   p += align_up((size_t)n * 4);
    int2*   oe      = (int2*)p;    p += align_up((size_t)n * 8);
    float*  W1t     = (float*)p;   p += align_up(64 * 32 * 4);
    float*  W2t     = (float*)p;   p += align_up(32 * 64 * 4);
    __half* xs      = (__half*)p;  p += align_up((size_t)n * 32 * 2);
    __half* xw2s    = (__half*)p;  p += align_up((size_t)n * 32 * 2);

    // 1) build: zero bucket counters, scatter with bulk range claiming
    hipMemsetAsync(bcnt, 0, (size_t)nbuck * 4, stream);
    scatter_direct_kernel<<<eb, TPB, 0, stream>>>(src, dst, bcnt, sortedb,
                                                  W1, W2, W1t, W2t, e, nbuck);
    bucket_sort_fill_kernel<<<nbuck, TPB, 0, stream>>>(sortedb, bcnt, x, slot,
                                                       dis, oe, xs, n, nbuck);

    // 2) fused layer-1 gather + MFMA dense middle
    gather1_dense_kernel<<<(n + 63) / 64, TPB, 0, stream>>>(xs, oe, slot, dis,
                                                            W1t, b1, W2t, xw2s, n);

    // 3) layer 2 gather + bias + relu + head (fused)
    gather2_head_kernel<<<(n + 63) / 64, TPB, 0, stream>>>(xw2s, dis, oe, slot,
                                                           b2, Wl, bl, out, n);
}